// Round 3
// baseline (234.109 us; speedup 1.0000x reference)
//
#include <hip/hip_runtime.h>

// LocalPathEncoderRobustAdvancedTemporal — R2: two-kernel split.
// out[b,l,:] = (Σ_f relu(x_f*W1 + b1)) @ W2 + 8*b2   (8x FLOP collapse, exact)
//
// R1 was latency-bound (VALUBusy 22%, MfmaUtil 2.6%, HBM 13%): serial per-block
// phases, idle waves during stats, 12 waves/CU. R2 splits:
//  * lpe_feats: 2 samples/block, ALL 256 threads do stats (feats in regs),
//    ~6KB LDS -> 16 waves/CU; writes g (bf16) rows to d_ws. W2^T bf16 prep
//    folded into first 64 blocks.
//  * lpe_gemm: streaming [262144x128]@[128x128]: W2^T in LDS (pitch 136 ->
//    uniform b128 bank-group spread), g fragments direct from global,
//    float4 C stores. Memory-bound ~30us floor.
// Fallback: proven R1 fused kernel when ws_size < 67.2 MB.

#define EPSF 1e-6f
#define LDB 136              // W2T LDS pitch in shorts

typedef __attribute__((ext_vector_type(8))) short bf16x8;
typedef __attribute__((ext_vector_type(4))) float f32x4;

__device__ inline short f2bf(float x) {           // fp32 -> bf16 (RNE)
    unsigned u = __float_as_uint(x);
    return (short)((u + 0x7fffu + ((u >> 16) & 1u)) >> 16);
}

// ---------------- kernel 1: stats + g (bf16) -> ws ----------------
__launch_bounds__(256, 4)
__global__ void lpe_feats(const int* __restrict__ src_ids,
                          const int* __restrict__ dst_ids,
                          const int* __restrict__ src_nid,
                          const int* __restrict__ dst_nid,
                          const float* __restrict__ t_now,
                          const float* __restrict__ src_t,
                          const float* __restrict__ dst_t,
                          const float* __restrict__ W1,
                          const float* __restrict__ b1,
                          const float* __restrict__ W2,
                          short* __restrict__ w2t,
                          short* __restrict__ gws)
{
    __shared__ int2  s_idt[256];
    __shared__ int   s_rank[256];
    __shared__ float s_avg[256];
    __shared__ float s_rec[256];
    __shared__ float s_w1[128];
    __shared__ float s_b1[128];

    const int tid = threadIdx.x;

    // fold W2^T bf16 prep into first 64 blocks (16384 elems total)
    if (blockIdx.x < 64) {
        const int idx = blockIdx.x * 256 + tid;
        const int k = idx >> 7, n = idx & 127;
        w2t[n * 128 + k] = f2bf(W2[idx]);
    }

    const int h    = tid >> 7;                 // which sample in this block
    const int b    = (blockIdx.x << 1) | h;
    const int t    = tid & 127;                // row within sample
    const int side = t >> 6;
    const int i    = tid & 63;
    const int base = tid & ~63;                // own-side base in LDS

    const int*   idp = side ? dst_ids : src_ids;
    const float* tp  = side ? dst_t   : src_t;
    const int   my_id = idp[b * 64 + i];
    const float my_t  = tp[b * 64 + i];
    s_idt[tid] = make_int2(my_id, __float_as_int(my_t));
    if (tid < 128) { s_w1[tid] = W1[tid]; s_b1[tid] = b1[tid]; }
    __syncthreads();

    // ---- group stats ----
    int n_g = 0, rank = 0;
    float tmax = -3.4e38f, tmin = 3.4e38f;
    for (int j = 0; j < 64; ++j) {
        const int2 e = s_idt[base + j];
        const float tj = __int_as_float(e.y);
        if (e.x == my_id) {
            ++n_g;
            tmax = fmaxf(tmax, tj);
            tmin = fminf(tmin, tj);
            if (tj < my_t || (tj == my_t && j < i)) ++rank;
        }
    }
    s_rank[tid] = rank;
    const float avg   = (n_g > 1) ? (tmax - tmin) / (float)(n_g - 1) : 0.f;
    const float avg_m = (my_id != 0) ? avg : 0.f;
    s_avg[tid] = avg_m;
    __syncthreads();

    // ---- recent_iat ----
    const int split = n_g >> 1;
    float tsplit = 0.f;
    for (int j = 0; j < 64; ++j) {
        const int2 e = s_idt[base + j];
        if (e.x == my_id && s_rank[base + j] == split)
            tsplit = __int_as_float(e.y);
    }
    const float rec   = (n_g >= 4)
        ? (tmax - tsplit) / fmaxf((float)(n_g - split - 1), 1.f) : 0.f;
    const float rec_m = (my_id != 0) ? rec : 0.f;
    s_rec[tid] = rec_m;
    __syncthreads();

    // ---- cross features ----
    const int   obase = base ^ 64;
    const float cur   = t_now[b];
    const int other_node = side ? src_nid[b] : dst_nid[b];

    int c_other = 0, first_idx = -1;
    float last_t = 0.f;
    for (int j = 0; j < 64; ++j) {
        const int2 e = s_idt[obase + j];
        if (e.x == my_id) {
            ++c_other;
            if (e.x != 0) { last_t = __int_as_float(e.y); if (first_idx < 0) first_idx = j; }
        }
    }
    const float c_self = (float)n_g;
    const float co     = (float)c_other;
    const float m      = (my_id != 0) ? 1.f : 0.f;
    const float x0 = m * c_self;
    const float x1 = m * co;
    const float x2 = m * ((my_id == other_node) ? 1.f : 0.f);
    const float x3 = m * ((c_other > 0) ? 1.f : 0.f);
    const float x4 = m * ((c_other > 0) ? c_self / (co + EPSF) : 0.f);
    const float rcy_s = cur - my_t;
    const float rcy_o = cur - last_t;
    const float x5 = m * ((rcy_s > EPSF) ? rcy_o / (rcy_s + EPSF) : 0.f);
    const float iat_o  = (first_idx >= 0) ? s_avg[obase + first_idx] : 0.f;
    const float x6 = m * ((iat_o > EPSF) ? avg_m / (iat_o + EPSF) : 0.f);
    const float riat_o = (first_idx >= 0) ? s_rec[obase + first_idx] : 0.f;
    const float x7 = m * ((riat_o > EPSF) ? rec_m / (riat_o + EPSF) : 0.f);

    // ---- g[d] = sum_f relu(w1[d]*x_f + b1[d]) -> bf16 row in ws ----
    short* gp = gws + ((long)b * 128 + t) * 128;
    #pragma unroll
    for (int dc = 0; dc < 8; ++dc) {
        alignas(16) short buf[16];
        #pragma unroll
        for (int u = 0; u < 16; ++u) {
            const float w  = s_w1[dc * 16 + u];
            const float bb = s_b1[dc * 16 + u];
            float s = fmaxf(fmaf(x0, w, bb), 0.f);
            s += fmaxf(fmaf(x1, w, bb), 0.f);
            s += fmaxf(fmaf(x2, w, bb), 0.f);
            s += fmaxf(fmaf(x3, w, bb), 0.f);
            s += fmaxf(fmaf(x4, w, bb), 0.f);
            s += fmaxf(fmaf(x5, w, bb), 0.f);
            s += fmaxf(fmaf(x6, w, bb), 0.f);
            s += fmaxf(fmaf(x7, w, bb), 0.f);
            buf[u] = f2bf(s);
        }
        *(bf16x8*)&gp[dc * 16]     = *(const bf16x8*)&buf[0];
        *(bf16x8*)&gp[dc * 16 + 8] = *(const bf16x8*)&buf[8];
    }
}

// ---------------- kernel 2: streaming GEMM g @ W2 + 8*b2 ----------------
__launch_bounds__(256, 3)
__global__ void lpe_gemm(const short* __restrict__ w2t,
                         const short* __restrict__ gws,
                         const float* __restrict__ b2,
                         float* __restrict__ out)
{
    __shared__ short W2T[128 * LDB];   // 34816 B

    const int tid = threadIdx.x;
    // stage W2^T: coalesced global b128 reads -> padded LDS (uniform bank spread)
    #pragma unroll
    for (int it = 0; it < 8; ++it) {
        const int fi = it * 256 + tid;        // 2048 fragments of 8 shorts
        const int n = fi >> 4, c = fi & 15;
        *(bf16x8*)&W2T[n * LDB + c * 8] = *(const bf16x8*)&w2t[n * 128 + c * 8];
    }
    __syncthreads();

    const int lane = tid & 63, wv = tid >> 6;
    const int quad = lane >> 4, ln = lane & 15;
    const int rbase = blockIdx.x * 256 + wv * 64;

    // B fragments: g rows, direct from global. bf[rg][kk]
    bf16x8 bf[4][4];
    #pragma unroll
    for (int rg = 0; rg < 4; ++rg) {
        const short* gp = gws + ((long)(rbase + rg * 16 + ln)) * 128;
        #pragma unroll
        for (int kk = 0; kk < 4; ++kk)
            bf[rg][kk] = *(const bf16x8*)&gp[kk * 32 + quad * 8];
    }

    const long side_stride = 2048L * 64L * 128L;
    #pragma unroll
    for (int et = 0; et < 8; ++et) {
        bf16x8 af[4];
        #pragma unroll
        for (int kk = 0; kk < 4; ++kk)
            af[kk] = *(const bf16x8*)&W2T[(et * 16 + ln) * LDB + kk * 32 + quad * 8];

        f32x4 acc[4];
        #pragma unroll
        for (int rg = 0; rg < 4; ++rg) acc[rg] = (f32x4){0.f, 0.f, 0.f, 0.f};
        #pragma unroll
        for (int kk = 0; kk < 4; ++kk)
            #pragma unroll
            for (int rg = 0; rg < 4; ++rg)
                acc[rg] = __builtin_amdgcn_mfma_f32_16x16x32_bf16(af[kk], bf[rg][kk], acc[rg], 0, 0, 0);

        const int e0 = et * 16 + quad * 4;
        const f32x4 bb4 = *(const f32x4*)&b2[e0];
        const f32x4 badd = bb4 * 8.f;
        #pragma unroll
        for (int rg = 0; rg < 4; ++rg) {
            const int r  = rbase + rg * 16 + ln;
            const int bq = r >> 7, tq = r & 127;
            const int sd = tq >> 6, ii = tq & 63;
            float* po = out + (long)sd * side_stride + ((long)(bq * 64 + ii)) * 128 + e0;
            *(f32x4*)po = acc[rg] + badd;
        }
    }
}

// ---------------- fallback: proven R1 fused kernel ----------------
__launch_bounds__(256, 3)
__global__ void lpe_fused(const int* __restrict__ src_ids,
                          const int* __restrict__ dst_ids,
                          const int* __restrict__ src_nid,
                          const int* __restrict__ dst_nid,
                          const float* __restrict__ t_now,
                          const float* __restrict__ src_t,
                          const float* __restrict__ dst_t,
                          const float* __restrict__ W1,
                          const float* __restrict__ b1,
                          const float* __restrict__ W2,
                          const float* __restrict__ b2,
                          float* __restrict__ out)
{
    __shared__ short W2T[128 * LDB];
    __shared__ int2  s_idt[128];
    __shared__ int   s_rank[128];
    __shared__ float s_avg[128];
    __shared__ float s_rec[128];
    __shared__ float s_feats[128][8];
    __shared__ float s_w1[128];
    __shared__ float s_b1[128];

    const int b   = blockIdx.x;
    const int tid = threadIdx.x;

    int   my_id = 0;  float my_t = 0.f;
    int   n_g = 0;    float tmax_g = 0.f;
    float avg_m = 0.f, rec_m = 0.f;

    if (tid < 128) {
        const int side = tid >> 6, i = tid & 63;
        const int*   idp = side ? dst_ids : src_ids;
        const float* tp  = side ? dst_t   : src_t;
        my_id = idp[b * 64 + i];
        my_t  = tp[b * 64 + i];
        s_idt[tid] = make_int2(my_id, __float_as_int(my_t));
        s_w1[tid]  = W1[tid];
        s_b1[tid]  = b1[tid];
    } else {
        const int t2 = tid - 128;
        for (int u = t2; u < 8192; u += 128) {
            const int k = u >> 7, n = u & 127;
            W2T[n * LDB + k] = f2bf(W2[k * 128 + n]);
        }
    }
    __syncthreads();

    if (tid < 128) {
        const int base = tid & 64, i = tid & 63;
        int n = 0, rank = 0;
        float tmax = -3.4e38f, tmin = 3.4e38f;
        for (int j = 0; j < 64; ++j) {
            const int2 e = s_idt[base + j];
            const float tj = __int_as_float(e.y);
            if (e.x == my_id) {
                ++n;
                tmax = fmaxf(tmax, tj);
                tmin = fminf(tmin, tj);
                if (tj < my_t || (tj == my_t && j < i)) ++rank;
            }
        }
        n_g = n; tmax_g = tmax;
        s_rank[tid] = rank;
        const float avg = (n > 1) ? (tmax - tmin) / (float)(n - 1) : 0.f;
        avg_m = (my_id != 0) ? avg : 0.f;
        s_avg[tid] = avg_m;
    } else {
        const int t2 = tid - 128;
        for (int u = t2 + 8192; u < 16384; u += 128) {
            const int k = u >> 7, n = u & 127;
            W2T[n * LDB + k] = f2bf(W2[k * 128 + n]);
        }
    }
    __syncthreads();

    if (tid < 128) {
        const int base = tid & 64;
        const int split = n_g >> 1;
        float tsplit = 0.f;
        for (int j = 0; j < 64; ++j) {
            const int2 e = s_idt[base + j];
            if (e.x == my_id && s_rank[base + j] == split)
                tsplit = __int_as_float(e.y);
        }
        const float denom = fmaxf((float)(n_g - split - 1), 1.f);
        const float rec = (n_g >= 4) ? (tmax_g - tsplit) / denom : 0.f;
        rec_m = (my_id != 0) ? rec : 0.f;
        s_rec[tid] = rec_m;
    }
    __syncthreads();

    if (tid < 128) {
        const int side  = tid >> 6;
        const int obase = 64 - (tid & 64);
        const float cur = t_now[b];
        const int other_node = side ? src_nid[b] : dst_nid[b];

        int c_other = 0, first_idx = -1;
        float last_t = 0.f;
        for (int j = 0; j < 64; ++j) {
            const int2 e = s_idt[obase + j];
            if (e.x == my_id) {
                ++c_other;
                if (e.x != 0) {
                    last_t = __int_as_float(e.y);
                    if (first_idx < 0) first_idx = j;
                }
            }
        }
        const float c_self = (float)n_g;
        const float co     = (float)c_other;
        const float f_is   = (my_id == other_node) ? 1.f : 0.f;
        const float f_conn = (c_other > 0) ? 1.f : 0.f;
        const float f_freq = (c_other > 0) ? c_self / (co + EPSF) : 0.f;
        const float rcy_s  = cur - my_t;
        const float rcy_o  = cur - last_t;
        const float f_temp = (rcy_s > EPSF) ? rcy_o / (rcy_s + EPSF) : 0.f;
        const float iat_o  = (first_idx >= 0) ? s_avg[obase + first_idx] : 0.f;
        const float f_iat  = (iat_o > EPSF) ? avg_m / (iat_o + EPSF) : 0.f;
        const float riat_o = (first_idx >= 0) ? s_rec[obase + first_idx] : 0.f;
        const float f_riat = (riat_o > EPSF) ? rec_m / (riat_o + EPSF) : 0.f;
        const float m = (my_id != 0) ? 1.f : 0.f;
        s_feats[tid][0] = m * c_self;
        s_feats[tid][1] = m * co;
        s_feats[tid][2] = m * f_is;
        s_feats[tid][3] = m * f_conn;
        s_feats[tid][4] = m * f_freq;
        s_feats[tid][5] = m * f_temp;
        s_feats[tid][6] = m * f_iat;
        s_feats[tid][7] = m * f_riat;
    }
    __syncthreads();

    const int lane = tid & 63, wv = tid >> 6;
    const int quad = lane >> 4, ln = lane & 15;

    f32x4 fx[2][2];
    #pragma unroll
    for (int mi = 0; mi < 2; ++mi) {
        const int row = wv * 32 + mi * 16 + ln;
        fx[mi][0] = *(const f32x4*)&s_feats[row][0];
        fx[mi][1] = *(const f32x4*)&s_feats[row][4];
    }

    f32x4 acc[2][8];
    #pragma unroll
    for (int mi = 0; mi < 2; ++mi)
        #pragma unroll
        for (int et = 0; et < 8; ++et)
            acc[mi][et] = (f32x4){0.f, 0.f, 0.f, 0.f};

    #pragma unroll
    for (int kk = 0; kk < 4; ++kk) {
        const int kof = kk * 32 + quad * 8;
        const f32x4 w1a = *(const f32x4*)&s_w1[kof];
        const f32x4 w1b = *(const f32x4*)&s_w1[kof + 4];
        const f32x4 b1a = *(const f32x4*)&s_b1[kof];
        const f32x4 b1b = *(const f32x4*)&s_b1[kof + 4];
        bf16x8 gf[2];
        #pragma unroll
        for (int mi = 0; mi < 2; ++mi) {
            const f32x4 xa = fx[mi][0], xb = fx[mi][1];
            #pragma unroll
            for (int j = 0; j < 8; ++j) {
                const float w  = (j < 4) ? w1a[j] : w1b[j - 4];
                const float bb = (j < 4) ? b1a[j] : b1b[j - 4];
                float s = fmaxf(fmaf(xa[0], w, bb), 0.f);
                s += fmaxf(fmaf(xa[1], w, bb), 0.f);
                s += fmaxf(fmaf(xa[2], w, bb), 0.f);
                s += fmaxf(fmaf(xa[3], w, bb), 0.f);
                s += fmaxf(fmaf(xb[0], w, bb), 0.f);
                s += fmaxf(fmaf(xb[1], w, bb), 0.f);
                s += fmaxf(fmaf(xb[2], w, bb), 0.f);
                s += fmaxf(fmaf(xb[3], w, bb), 0.f);
                gf[mi][j] = f2bf(s);
            }
        }
        #pragma unroll
        for (int et = 0; et < 8; ++et) {
            const bf16x8 af = *(const bf16x8*)&W2T[(et * 16 + ln) * LDB + kof];
            acc[0][et] = __builtin_amdgcn_mfma_f32_16x16x32_bf16(af, gf[0], acc[0][et], 0, 0, 0);
            acc[1][et] = __builtin_amdgcn_mfma_f32_16x16x32_bf16(af, gf[1], acc[1][et], 0, 0, 0);
        }
    }

    const long side_stride = 2048L * 64L * 128L;
    #pragma unroll
    for (int et = 0; et < 8; ++et) {
        const int e0 = et * 16 + quad * 4;
        const f32x4 bb4 = *(const f32x4*)&b2[e0];
        const f32x4 badd = bb4 * 8.f;
        #pragma unroll
        for (int mi = 0; mi < 2; ++mi) {
            const int row  = wv * 32 + mi * 16 + ln;
            const int side = row >> 6, i = row & 63;
            float* po = out + (long)side * side_stride + ((long)(b * 64 + i)) * 128 + e0;
            *(f32x4*)po = acc[mi][et] + badd;
        }
    }
}

extern "C" void kernel_launch(void* const* d_in, const int* in_sizes, int n_in,
                              void* d_out, int out_size, void* d_ws, size_t ws_size,
                              hipStream_t stream) {
    (void)in_sizes; (void)n_in; (void)out_size;
    const int*   src_ids = (const int*)  d_in[0];
    const int*   dst_ids = (const int*)  d_in[1];
    const int*   src_nid = (const int*)  d_in[2];
    const int*   dst_nid = (const int*)  d_in[3];
    const float* t_now   = (const float*)d_in[4];
    const float* src_t   = (const float*)d_in[5];
    const float* dst_t   = (const float*)d_in[6];
    const float* W1      = (const float*)d_in[7];
    const float* b1      = (const float*)d_in[8];
    const float* W2      = (const float*)d_in[9];
    const float* b2      = (const float*)d_in[10];
    float* out = (float*)d_out;

    const size_t WS_NEEDED = 32768 + (size_t)262144 * 256;   // w2t + g = 67.1 MB
    if (ws_size >= WS_NEEDED) {
        short* w2t = (short*)d_ws;
        short* gws = (short*)d_ws + 16384;
        lpe_feats<<<1024, 256, 0, stream>>>(src_ids, dst_ids, src_nid, dst_nid,
                                            t_now, src_t, dst_t, W1, b1, W2,
                                            w2t, gws);
        lpe_gemm<<<1024, 256, 0, stream>>>(w2t, gws, b2, out);
    } else {
        lpe_fused<<<2048, 256, 0, stream>>>(src_ids, dst_ids, src_nid, dst_nid,
                                            t_now, src_t, dst_t, W1, b1, W2, b2,
                                            out);
    }
}

// Round 4
// 212.475 us; speedup vs baseline: 1.1018x; 1.1018x over previous
//
#include <hip/hip_runtime.h>

// LocalPathEncoderRobustAdvancedTemporal — R3: fused, id-indexed LDS tables.
// out[b,l,:] = (Σ_f relu(x_f*W1 + b1)) @ W2 + 8*b2   (8x FLOP collapse, exact)
//
// R2 split regressed: g spill added 128MB HBM (+20us). Back to fused; attack
// block latency instead:
//  * Group stats are group-uniform -> publish to LDS tables indexed by
//    neighbor id (512 nodes): n/avg by all members (benign race, same value),
//    rec by the unique rank==split member, last_t by the unique last-position
//    member. Cross-side features become O(1) table reads (kills 2 of 3
//    64-iter loops).
//  * 2 samples/block: all 256 threads compute stats (no idle waves).
//  * W2^T bf16 prepped once to ws; GEMM reads it from L2 (no 35KB LDS stage)
//    -> 45KB LDS -> 3 blocks/CU.
//  * Remaining 64-iter loop unrolled x8; g computed in registers; R2's
//    verified MFMA fragment/store mapping (float4 coalesced C stores).

#define EPSF 1e-6f
#define LDB 136

typedef __attribute__((ext_vector_type(8))) short bf16x8;
typedef __attribute__((ext_vector_type(4))) float f32x4;

__device__ inline short f2bf(float x) {           // fp32 -> bf16 (RNE)
    unsigned u = __float_as_uint(x);
    return (short)((u + 0x7fffu + ((u >> 16) & 1u)) >> 16);
}

__global__ void w2t_prep(const float* __restrict__ W2, short* __restrict__ w2t) {
    const int idx = blockIdx.x * 256 + threadIdx.x;   // 16384
    const int k = idx >> 7, n = idx & 127;
    w2t[n * 128 + k] = f2bf(W2[idx]);
}

template <bool FROMWS>
__launch_bounds__(256, 3)
__global__ void lpe_fused2(const int* __restrict__ src_ids,
                           const int* __restrict__ dst_ids,
                           const int* __restrict__ src_nid,
                           const int* __restrict__ dst_nid,
                           const float* __restrict__ t_now,
                           const float* __restrict__ src_t,
                           const float* __restrict__ dst_t,
                           const float* __restrict__ W1,
                           const float* __restrict__ b1,
                           const float* __restrict__ W2,
                           const float* __restrict__ b2,
                           const short* __restrict__ w2t,
                           float* __restrict__ out)
{
    __shared__ int2  s_idt[256];          // (id, t) per local row
    __shared__ float s_nt[4][512];        // group size   per (side-sample, id)
    __shared__ float s_avgt[4][512];      // avg_iat      (valid if n>0)
    __shared__ float s_rect[4][512];      // recent_iat   (valid if n>0)
    __shared__ float s_lastt[4][512];     // last-occurrence time (valid if n>0)
    __shared__ float s_feats[256][9];     // 8 feats, pad to 9 (bank spread)
    __shared__ float s_w1[128], s_b1[128];
    __shared__ short W2T[FROMWS ? 8 : 128 * LDB];   // fallback-only stage

    const int tid   = threadIdx.x;
    const int r     = tid;                // local row 0..255 (2 samples)
    const int h     = r >> 7;             // sample within block
    const int b     = blockIdx.x * 2 + h;
    const int side  = (r >> 6) & 1;
    const int i     = r & 63;
    const int ss    = r >> 6;             // side-sample slot 0..3
    const int sbase = r & ~63;            // own-side base in s_idt

    // zero the n-table (only table needing init; others are n>0-guarded)
    #pragma unroll
    for (int u = tid; u < 2048; u += 256) ((float*)s_nt)[u] = 0.f;

    const int*   idp = side ? dst_ids : src_ids;
    const float* tp  = side ? dst_t   : src_t;
    const int   my_id = idp[b * 64 + i];
    const float my_t  = tp[b * 64 + i];
    s_idt[r] = make_int2(my_id, __float_as_int(my_t));
    if (tid < 128) { s_w1[tid] = W1[tid]; s_b1[tid] = b1[tid]; }
    if constexpr (!FROMWS) {
        for (int u = tid; u < 16384; u += 256) {
            const int k = u >> 7, n = u & 127;
            W2T[n * LDB + k] = f2bf(W2[u]);
        }
    }
    __syncthreads();

    // ---- single O(L) loop: n, tmax, tmin, rank, has-later ----
    int n = 0, rank = 0, later = 0;
    float tmax = -3.4e38f, tmin = 3.4e38f;
    #pragma unroll 8
    for (int j = 0; j < 64; ++j) {
        const int2 e = s_idt[sbase + j];
        const float tj = __int_as_float(e.y);
        if (e.x == my_id) {
            ++n;
            tmax = fmaxf(tmax, tj);
            tmin = fminf(tmin, tj);
            if (tj < my_t || (tj == my_t && j < i)) ++rank;
            if (j > i) later = 1;
        }
    }
    const float nf    = (float)n;
    const int   split = n >> 1;
    const float avg   = (n > 1) ? (tmax - tmin) / (nf - 1.f) : 0.f;
    if (my_id != 0) {
        s_nt[ss][my_id]   = nf;    // benign race: same value from all members
        s_avgt[ss][my_id] = avg;
        if (rank == split)         // unique member: sorted(ts)[n//2] == my_t
            s_rect[ss][my_id] = (n >= 4)
                ? (tmax - my_t) / fmaxf(nf - (float)split - 1.f, 1.f) : 0.f;
        if (!later)                // unique member: last occurrence
            s_lastt[ss][my_id] = my_t;
    }
    __syncthreads();

    // ---- cross features: O(1) table reads ----
    {
        const int   os    = ss ^ 1;                  // other side, same sample
        const float avg_m = (my_id != 0) ? avg : 0.f;
        const float rec_m = (my_id != 0) ? s_rect[ss][my_id] : 0.f;
        const float n_o   = (my_id != 0) ? s_nt[os][my_id] : 0.f;
        const bool  hit   = n_o > 0.f;
        const float avg_o = hit ? s_avgt[os][my_id] : 0.f;
        const float rec_o = hit ? s_rect[os][my_id] : 0.f;
        const float lastt = hit ? s_lastt[os][my_id] : 0.f;
        const float cur   = t_now[b];
        const int other_node = side ? src_nid[b] : dst_nid[b];
        const float m = (my_id != 0) ? 1.f : 0.f;

        const float rcy_s = cur - my_t;
        const float rcy_o = cur - lastt;
        s_feats[r][0] = m * nf;
        s_feats[r][1] = m * n_o;
        s_feats[r][2] = m * ((my_id == other_node) ? 1.f : 0.f);
        s_feats[r][3] = m * (hit ? 1.f : 0.f);
        s_feats[r][4] = m * (hit ? nf / (n_o + EPSF) : 0.f);
        s_feats[r][5] = m * ((rcy_s > EPSF) ? rcy_o / (rcy_s + EPSF) : 0.f);
        s_feats[r][6] = m * ((avg_o > EPSF) ? avg_m / (avg_o + EPSF) : 0.f);
        s_feats[r][7] = m * ((rec_o > EPSF) ? rec_m / (rec_o + EPSF) : 0.f);
    }
    __syncthreads();

    // ---- GEMM: wave wv owns rows [wv*64, wv*64+64), all 8 e-tiles ----
    const int lane = tid & 63, wv = tid >> 6;
    const int quad = lane >> 4, ln = lane & 15;

    float fxr[4][8];
    #pragma unroll
    for (int rg = 0; rg < 4; ++rg) {
        const int row = wv * 64 + rg * 16 + ln;
        #pragma unroll
        for (int j = 0; j < 8; ++j) fxr[rg][j] = s_feats[row][j];
    }

    bf16x8 gf[4][4];                     // g fragments [row-tile][k-block]
    #pragma unroll
    for (int kk = 0; kk < 4; ++kk) {
        const int kb = kk * 32 + quad * 8;
        #pragma unroll
        for (int rg = 0; rg < 4; ++rg) {
            #pragma unroll
            for (int u = 0; u < 8; ++u) {
                const float w  = s_w1[kb + u];
                const float bb = s_b1[kb + u];
                float s = fmaxf(fmaf(fxr[rg][0], w, bb), 0.f);
                s += fmaxf(fmaf(fxr[rg][1], w, bb), 0.f);
                s += fmaxf(fmaf(fxr[rg][2], w, bb), 0.f);
                s += fmaxf(fmaf(fxr[rg][3], w, bb), 0.f);
                s += fmaxf(fmaf(fxr[rg][4], w, bb), 0.f);
                s += fmaxf(fmaf(fxr[rg][5], w, bb), 0.f);
                s += fmaxf(fmaf(fxr[rg][6], w, bb), 0.f);
                s += fmaxf(fmaf(fxr[rg][7], w, bb), 0.f);
                gf[rg][kk][u] = f2bf(s);
            }
        }
    }

    const long side_stride = 2048L * 64L * 128L;
    #pragma unroll
    for (int et = 0; et < 8; ++et) {
        bf16x8 af[4];
        #pragma unroll
        for (int kk = 0; kk < 4; ++kk) {
            if constexpr (FROMWS)
                af[kk] = *(const bf16x8*)&w2t[(et * 16 + ln) * 128 + kk * 32 + quad * 8];
            else
                af[kk] = *(const bf16x8*)&W2T[(et * 16 + ln) * LDB + kk * 32 + quad * 8];
        }
        f32x4 acc[4];
        #pragma unroll
        for (int rg = 0; rg < 4; ++rg) acc[rg] = (f32x4){0.f, 0.f, 0.f, 0.f};
        #pragma unroll
        for (int kk = 0; kk < 4; ++kk)
            #pragma unroll
            for (int rg = 0; rg < 4; ++rg)
                acc[rg] = __builtin_amdgcn_mfma_f32_16x16x32_bf16(af[kk], gf[rg][kk], acc[rg], 0, 0, 0);

        const int e0 = et * 16 + quad * 4;
        const f32x4 badd = *(const f32x4*)&b2[e0] * 8.f;
        #pragma unroll
        for (int rg = 0; rg < 4; ++rg) {
            const int row = wv * 64 + rg * 16 + ln;
            const int h2 = row >> 7, sd = (row >> 6) & 1, ii = row & 63;
            const long bq = (long)blockIdx.x * 2 + h2;
            *(f32x4*)&out[(long)sd * side_stride + (bq * 64 + ii) * 128 + e0]
                = acc[rg] + badd;
        }
    }
}

extern "C" void kernel_launch(void* const* d_in, const int* in_sizes, int n_in,
                              void* d_out, int out_size, void* d_ws, size_t ws_size,
                              hipStream_t stream) {
    (void)in_sizes; (void)n_in; (void)out_size;
    const int*   src_ids = (const int*)  d_in[0];
    const int*   dst_ids = (const int*)  d_in[1];
    const int*   src_nid = (const int*)  d_in[2];
    const int*   dst_nid = (const int*)  d_in[3];
    const float* t_now   = (const float*)d_in[4];
    const float* src_t   = (const float*)d_in[5];
    const float* dst_t   = (const float*)d_in[6];
    const float* W1      = (const float*)d_in[7];
    const float* b1      = (const float*)d_in[8];
    const float* W2      = (const float*)d_in[9];
    const float* b2      = (const float*)d_in[10];
    float* out = (float*)d_out;

    if (ws_size >= (size_t)(128 * 128 * 2)) {
        short* w2t = (short*)d_ws;
        w2t_prep<<<64, 256, 0, stream>>>(W2, w2t);
        lpe_fused2<true><<<1024, 256, 0, stream>>>(src_ids, dst_ids, src_nid, dst_nid,
                                                   t_now, src_t, dst_t, W1, b1, W2, b2,
                                                   w2t, out);
    } else {
        lpe_fused2<false><<<1024, 256, 0, stream>>>(src_ids, dst_ids, src_nid, dst_nid,
                                                    t_now, src_t, dst_t, W1, b1, W2, b2,
                                                    nullptr, out);
    }
}